// Round 9
// baseline (3403.277 us; speedup 1.0000x reference)
//
#include <hip/hip_runtime.h>
#include <cmath>

#define NB   16
#define LL   1024
#define DD   512
#define NCLS 64

// ---------------------------------------------- fused embed-gather + proj GEMM
// 128x64 tile, 4x8 acc/thread. C[m][n] = b1[n]+b2[n] + sum_k emb[x[m]][k]*W[n][k]
__global__ __launch_bounds__(256) void k_gemm_embed(
    const int* __restrict__ x, const float* __restrict__ emb,
    const float* __restrict__ W, const float* __restrict__ b1,
    const float* __restrict__ b2, float* __restrict__ C)
{
  __shared__ __align__(16) float As[32][132];  // [k][m], +4 pad
  __shared__ __align__(16) float Ws[32][68];   // [k][n], +4 pad
  const int tid = threadIdx.x;
  const int n0 = (blockIdx.x & 7) * 64;
  const int m0 = (blockIdx.x >> 3) * 128;      // 1024 blocks total
  const int tm = tid & 31, tn = tid >> 5;      // 32 x 8 thread grid
  float acc[4][8] = {};

  const int rA = tid >> 1, qA = (tid & 1) * 4;
  const long arow = (long)x[m0 + rA] * DD;
  const int rW = tid >> 2, qW = (tid & 3) * 2;
  const long wrow = (long)(n0 + rW) * DD;

  for (int k0 = 0; k0 < DD; k0 += 32) {
    float4 a4[4], w4[2];
    #pragma unroll
    for (int i = 0; i < 4; ++i) a4[i] = *(const float4*)(emb + arow + k0 + (qA + i) * 4);
    #pragma unroll
    for (int i = 0; i < 2; ++i) w4[i] = *(const float4*)(W + wrow + k0 + (qW + i) * 4);
    __syncthreads();
    #pragma unroll
    for (int i = 0; i < 4; ++i) {
      As[(qA+i)*4+0][rA] = a4[i].x; As[(qA+i)*4+1][rA] = a4[i].y;
      As[(qA+i)*4+2][rA] = a4[i].z; As[(qA+i)*4+3][rA] = a4[i].w;
    }
    #pragma unroll
    for (int i = 0; i < 2; ++i) {
      Ws[(qW+i)*4+0][rW] = w4[i].x; Ws[(qW+i)*4+1][rW] = w4[i].y;
      Ws[(qW+i)*4+2][rW] = w4[i].z; Ws[(qW+i)*4+3][rW] = w4[i].w;
    }
    __syncthreads();
    #pragma unroll
    for (int kk = 0; kk < 32; ++kk) {
      float4 a  = *(const float4*)&As[kk][tm * 4];
      float4 wA = *(const float4*)&Ws[kk][tn * 8];
      float4 wB = *(const float4*)&Ws[kk][tn * 8 + 4];
      const float av[4] = {a.x, a.y, a.z, a.w};
      const float wv[8] = {wA.x, wA.y, wA.z, wA.w, wB.x, wB.y, wB.z, wB.w};
      #pragma unroll
      for (int i = 0; i < 4; ++i)
        #pragma unroll
        for (int j = 0; j < 8; ++j)
          acc[i][j] += av[i] * wv[j];
    }
  }
  float bj[8];
  #pragma unroll
  for (int j = 0; j < 8; ++j)
    bj[j] = b1[n0 + tn * 8 + j] + b2[n0 + tn * 8 + j];
  #pragma unroll
  for (int i = 0; i < 4; ++i) {
    const int m = m0 + tm * 4 + i;
    float4 o1 = { acc[i][0]+bj[0], acc[i][1]+bj[1], acc[i][2]+bj[2], acc[i][3]+bj[3] };
    float4 o2 = { acc[i][4]+bj[4], acc[i][5]+bj[5], acc[i][6]+bj[6], acc[i][7]+bj[7] };
    *(float4*)(C + (long)m * DD + n0 + tn * 8)     = o1;
    *(float4*)(C + (long)m * DD + n0 + tn * 8 + 4) = o2;
  }
}

// ---------------------------------------------------------------- scan helpers
template<int CTRL>
__device__ __forceinline__ float dpp_add(float x) {
  int s = __builtin_amdgcn_update_dpp(0, __float_as_int(x), CTRL, 0xF, 0xF, true);
  return x + __int_as_float(s);
}
__device__ __forceinline__ float wave_red8(float y) {
  y = dpp_add<0xB1>(y);    // quad_perm xor1
  y = dpp_add<0x4E>(y);    // quad_perm xor2
  y = dpp_add<0x141>(y);   // row_half_mirror (other quad of the 8-group)
  return y;
}

__device__ __forceinline__ float fast_tanh(float x) {
  float e = __expf(2.0f * x);
  return 1.0f - __fdividef(2.0f, 1.0f + e);
}

__device__ __forceinline__ float poll_ld(const float* p) {
  return __hip_atomic_load(p, __ATOMIC_RELAXED, __HIP_MEMORY_SCOPE_AGENT);
}
__device__ __forceinline__ void enc_st(float* p, float v) {
  __hip_atomic_store(p, v + 2.0f, __ATOMIC_RELAXED, __HIP_MEMORY_SCOPE_AGENT);
}
// DWORD flag ops (plain global_load/store_dword with agent scope — NO RMW;
// r7 lesson: byte atomics lower to CAS loops and thrash the line).
__device__ __forceinline__ int flag_ld(const int* p) {
  return __hip_atomic_load(p, __ATOMIC_RELAXED, __HIP_MEMORY_SCOPE_AGENT);
}
__device__ __forceinline__ void flag_st(int* p) {
  __hip_atomic_store(p, 1, __ATOMIC_RELAXED, __HIP_MEMORY_SCOPE_AGENT);
}
__device__ __forceinline__ void st_drain() {
  asm volatile("s_waitcnt vmcnt(0)" ::: "memory");
}
__device__ __forceinline__ void dot64(const float* w, const float4* h4, float4& a) {
  #pragma unroll
  for (int q = 0; q < 16; ++q) {
    float4 h = h4[q];
    a.x += w[4*q+0]*h.x; a.y += w[4*q+1]*h.y;
    a.z += w[4*q+2]*h.z; a.w += w[4*q+3]*h.w;
  }
}
__device__ __forceinline__ float hsum4(const float4& a) { return (a.x+a.y)+(a.z+a.w); }

// ------------------------------------------------- persistent 2-layer RNN scan
// R6 BANKED STRUCTURE (2027us: sleep backoff + drain) + per-WG DWORD flags.
// Theory: the value-spin sweeps 32-64 lines/WG/iter -> ~16 line-req/cy/XCD,
// saturating L2 so every handshake op queues. Flags cut spin to 1-2 lines/WG:
// producer WG {stores 32 values -> per-wave vmcnt(0) -> __syncthreads (all
// waves' stores committed at L2, the same-XCD coherence point) -> tid0 stores
// ONE dword flag}. Consumers spin on the 16-dword (one line) flag row, then
// load values once. Fallback (ws too small) = byte-exact r6.
template<bool USE_FLAGS>
__global__ __launch_bounds__(256, 2) void k_scan_t(
    const float* __restrict__ W_ih, const float* __restrict__ W_hh,
    const float* __restrict__ b_ih, const float* __restrict__ b_hh,
    float* __restrict__ Bbuf,   // in: xproj layer1 -> h1+2 (in-place, encoded)
    float* __restrict__ Abuf,   // h2+2 (O2, encoded)
    int* __restrict__ flagB,    // [NB][LL][16] h1 ready flags (dword, 1 line/t)
    int* __restrict__ flagA)    // [NB][LL][16] h2 ready flags
{
  const int g = blockIdx.x;
  const int lay = g >> 8;          // 0: h1 chain, 1: h2 chain
  const int b = g & 15;            // batch
  const int j = (g & 255) >> 4;    // WG index within (layer,batch) [0,16)
  const int tid = threadIdx.x;
  const int lane = tid & 63;
  const int part = tid & 7;        // k-part [0,8), 64 elems each
  const int rl  = tid >> 3;        // row_local [0,32)
  const int row = j * 32 + rl;     // global hidden row
  const bool leader = (part == 0);
  const int fi = lane & 15;        // flag slot checked by this lane

  __shared__ __align__(16) float hS[2][8 * 68];  // recurrence-state stage, dbuf
  __shared__ __align__(16) float hT[2][8 * 68];  // h1 stage for layer-2's M2

  float* Bb = Bbuf + (long)b * LL * DD;
  float* Ab = Abuf + (long)b * LL * DD;
  int* fBb = flagB + (long)b * LL * 16;
  int* fAb = flagA + (long)b * LL * 16;

  const int i0 = tid, i1 = tid + 256;
  const int d0 = (i0 >> 6) * 68 + (i0 & 63);
  const int d1 = (i1 >> 6) * 68 + (i1 & 63);

  if (lay == 0) {
    // ------------ layer 1: h1(t) = tanh(xproj(t) + Whh1 . h1(t-1)) ----------
    float w1[64];
    {
      const float* p1 = W_hh + (long)row * DD + part * 64;
      #pragma unroll
      for (int q = 0; q < 64; ++q) w1[q] = p1[q];
    }
    #pragma unroll
    for (int q = 0; q < 64; ++q) asm volatile("" : "+v"(w1[q]));  // pin in VGPRs

    float xpv = 0.f, xnext = 0.f;
    if (leader) {
      xpv   = Bb[row];            // xproj(0)  (gemm completed: plain loads ok)
      xnext = Bb[DD + row];       // prefetch xproj(1) a full step ahead
      enc_st(Bb + row, fast_tanh(xpv));   // h1(0)
    }
    st_drain();
    if (USE_FLAGS) {
      __syncthreads();                     // all waves' h1(0) stores committed
      if (tid == 0) flag_st(fBb + 0 * 16 + j);
    }
    for (int t = 1; t < LL; ++t) {
      const int bufi = t & 1;
      xpv = xnext;
      if (leader && (t + 1 < LL)) xnext = Bb[(long)(t + 1) * DD + row];
      // ---- wait for h1(t-1) ----
      if (USE_FLAGS) {
        const int* fp = fBb + (long)(t - 1) * 16;
        int fv = flag_ld(fp + fi);
        while (!__all(fv == 1)) {
          __builtin_amdgcn_s_sleep(1);
          fv = flag_ld(fp + fi);
        }
      }
      const float* s1 = Bb + (long)(t - 1) * DD;
      float v0 = poll_ld(s1 + i0), v1 = poll_ld(s1 + i1);
      while (fminf(v0, v1) <= 1.0f) {   // flag path: effectively never loops
        if (!USE_FLAGS) __builtin_amdgcn_s_sleep(2);
        v0 = poll_ld(s1 + i0); v1 = poll_ld(s1 + i1);
      }
      hS[bufi][d0] = v0 - 2.0f; hS[bufi][d1] = v1 - 2.0f;
      __syncthreads();
      float4 a = {0.f, 0.f, 0.f, 0.f};
      dot64(w1, (const float4*)&hS[bufi][part * 68], a);
      float y = wave_red8(hsum4(a));
      if (leader) enc_st(Bb + (long)t * DD + row, fast_tanh(xpv + y));
      st_drain();
      if (USE_FLAGS) {
        __syncthreads();                   // all waves' h1(t) stores committed
        if (tid == 0) flag_st(fBb + (long)t * 16 + j);
      }
    }
  } else {
    // ------ layer 2: h2(t) = tanh(Wih2.h1(t) + bias2 + Whh2.h2(t-1)) --------
    float w2[64], w3[64];
    {
      const float* p2 = W_ih + (long)DD * DD + (long)row * DD + part * 64;
      const float* p3 = W_hh + (long)DD * DD + (long)row * DD + part * 64;
      #pragma unroll
      for (int q = 0; q < 64; ++q) { w2[q] = p2[q]; w3[q] = p3[q]; }
    }
    #pragma unroll
    for (int q = 0; q < 64; ++q) {
      asm volatile("" : "+v"(w2[q]));
      asm volatile("" : "+v"(w3[q]));
    }
    const float bias2 = b_ih[DD + row] + b_hh[DD + row];

    // prologue: xin2(0) = Wih2 . h1(0) + bias2
    float xin2;
    {
      if (USE_FLAGS) {
        const int* fp = fBb;               // flags for h1(0)
        int fv = flag_ld(fp + fi);
        while (!__all(fv == 1)) {
          __builtin_amdgcn_s_sleep(1);
          fv = flag_ld(fp + fi);
        }
      }
      const float* s1 = Bb;
      float v0 = poll_ld(s1 + i0), v1 = poll_ld(s1 + i1);
      while (fminf(v0, v1) <= 1.0f) {
        if (!USE_FLAGS) __builtin_amdgcn_s_sleep(2);
        v0 = poll_ld(s1 + i0); v1 = poll_ld(s1 + i1);
      }
      hT[1][d0] = v0 - 2.0f; hT[1][d1] = v1 - 2.0f;
      __syncthreads();
      float4 a = {0.f, 0.f, 0.f, 0.f};
      dot64(w2, (const float4*)&hT[1][part * 68], a);
      xin2 = wave_red8(hsum4(a)) + bias2;
    }
    // iter t: store h2(t) (using xin2(t)), then compute xin2(t+1) from h1(t+1)
    for (int t = 0; t < LL; ++t) {
      const int bufi = t & 1;
      const bool st2 = (t >= 1);        // h2(t-1) exists
      const bool st1 = (t + 1 < LL);    // need h1(t+1)
      {
        if (USE_FLAGS) {
          const int* fa = fAb + (long)(t - 1) * 16;
          const int* fb = fBb + (long)(t + 1) * 16;
          int a8 = 1, b8 = 1;
          if (st2) a8 = flag_ld(fa + fi);
          if (st1) b8 = flag_ld(fb + fi);
          while (!__all((a8 == 1) && (b8 == 1))) {
            __builtin_amdgcn_s_sleep(1);
            if (st2) a8 = flag_ld(fa + fi);
            if (st1) b8 = flag_ld(fb + fi);
          }
        }
        const float* s2 = Ab + (long)(t - 1) * DD;
        const float* s1 = Bb + (long)(t + 1) * DD;
        float u0 = 3.f, u1 = 3.f, v0 = 3.f, v1 = 3.f;
        if (st2) { u0 = poll_ld(s2 + i0); u1 = poll_ld(s2 + i1); }
        if (st1) { v0 = poll_ld(s1 + i0); v1 = poll_ld(s1 + i1); }
        while (fminf(fminf(u0, u1), fminf(v0, v1)) <= 1.0f) {
          if (!USE_FLAGS) __builtin_amdgcn_s_sleep(2);
          if (st2) { u0 = poll_ld(s2 + i0); u1 = poll_ld(s2 + i1); }
          if (st1) { v0 = poll_ld(s1 + i0); v1 = poll_ld(s1 + i1); }
        }
        if (st2) { hS[bufi][d0] = u0 - 2.0f; hS[bufi][d1] = u1 - 2.0f; }
        if (st1) { hT[bufi][d0] = v0 - 2.0f; hT[bufi][d1] = v1 - 2.0f; }
      }
      __syncthreads();
      // M3: h2(t) = tanh(xin2(t) + Whh2 . h2(t-1))
      float y3 = 0.f;
      if (st2) {
        float4 a = {0.f, 0.f, 0.f, 0.f};
        dot64(w3, (const float4*)&hS[bufi][part * 68], a);
        y3 = hsum4(a);
      }
      y3 = wave_red8(y3);
      if (leader) enc_st(Ab + (long)t * DD + row, fast_tanh(xin2 + y3));
      if (USE_FLAGS) {
        // M2 fills the store-propagation window; drain after it is ~free.
        if (st1) {
          float4 a = {0.f, 0.f, 0.f, 0.f};
          dot64(w2, (const float4*)&hT[bufi][part * 68], a);
          xin2 = wave_red8(hsum4(a)) + bias2;
        }
        st_drain();
        __syncthreads();                   // all waves' h2(t) stores committed
        if (tid == 0) flag_st(fAb + (long)t * 16 + j);
      } else {
        st_drain();
        if (st1) {
          float4 a = {0.f, 0.f, 0.f, 0.f};
          dot64(w2, (const float4*)&hT[bufi][part * 68], a);
          xin2 = wave_red8(hsum4(a)) + bias2;
        }
      }
    }
  }
}

// ------------------------------------------- attention row @ eos + decode head
// O2 is stored ENCODED (h+2). Decode: q explicitly; scores via qsum trick;
// att_z via sum(p)=1 -> subtract 2 at the end.
__global__ __launch_bounds__(256) void k_attn(
    const float* __restrict__ O2, const int* __restrict__ eos,
    const float* __restrict__ Wc, const float* __restrict__ bc,
    const float* __restrict__ Wd, const float* __restrict__ bd,
    float* __restrict__ out)
{
  const int b = blockIdx.x;
  const int tid = threadIdx.x;
  const int te = eos[b];
  __shared__ __align__(16) float q[DD];
  __shared__ float ps[LL];
  __shared__ float red[256];
  __shared__ __align__(16) float din[2 * DD];
  __shared__ __align__(16) float dvec[DD];
  const float* Ob = O2 + (long)b * LL * DD;
  const float4* Ob4 = (const float4*)Ob;

  float qpart = 0.f;
  for (int i = tid; i < DD; i += 256) {
    float v = Ob[(long)te * DD + i] - 2.0f;   // decode
    q[i] = v; qpart += v;
  }
  red[tid] = qpart; __syncthreads();
  for (int off = 128; off > 0; off >>= 1) {
    if (tid < off) red[tid] += red[tid + off];
    __syncthreads();
  }
  const float qsum = red[0];
  __syncthreads();
  const float4* q4 = (const float4*)q;

  // masked scores: raw dot(o_enc, q) - 2*qsum == dot(o, q)
  for (int ss = tid; ss < LL; ss += 256) {
    float sc = -1.0e9f;
    if (ss < te) {
      float4 acc = {0.f, 0.f, 0.f, 0.f};
      for (int kq = 0; kq < 128; ++kq) {
        float4 o = Ob4[ss * 128 + kq];
        float4 qq = q4[kq];
        acc.x += o.x*qq.x; acc.y += o.y*qq.y; acc.z += o.z*qq.z; acc.w += o.w*qq.w;
      }
      sc = acc.x + acc.y + acc.z + acc.w - 2.0f * qsum;
    }
    ps[ss] = sc;
  }
  __syncthreads();
  float m = -3.0e38f;
  for (int ss = tid; ss < LL; ss += 256) m = fmaxf(m, ps[ss]);
  red[tid] = m; __syncthreads();
  for (int off = 128; off > 0; off >>= 1) {
    if (tid < off) red[tid] = fmaxf(red[tid], red[tid + off]);
    __syncthreads();
  }
  m = red[0]; __syncthreads();
  float lsum = 0.f;
  for (int ss = tid; ss < LL; ss += 256) {
    float e = expf(ps[ss] - m);
    ps[ss] = e; lsum += e;
  }
  __syncthreads();
  red[tid] = lsum; __syncthreads();
  for (int off = 128; off > 0; off >>= 1) {
    if (tid < off) red[tid] += red[tid + off];
    __syncthreads();
  }
  const float inv = 1.0f / red[0];
  __syncthreads();
  for (int ss = tid; ss < LL; ss += 256) ps[ss] *= inv;
  __syncthreads();

  // att_z (encoded: sum p*o_enc - 2 since sum p = 1), z-copy (already decoded)
  if (tid < 128) {
    float4 acc = {0.f, 0.f, 0.f, 0.f};
    for (int ss = 0; ss < LL; ++ss) {
      float p = ps[ss];
      if (p != 0.0f) {
        float4 o = Ob4[ss * 128 + tid];
        acc.x += p*o.x; acc.y += p*o.y; acc.z += p*o.z; acc.w += p*o.w;
      }
    }
    acc.x -= 2.0f; acc.y -= 2.0f; acc.z -= 2.0f; acc.w -= 2.0f;
    ((float4*)din)[tid] = acc;
  } else {
    const int c = tid - 128;
    ((float4*)din)[128 + c] = q4[c];
  }
  __syncthreads();

  const float4* din4 = (const float4*)din;
  for (int jj = tid; jj < DD; jj += 256) {
    const float4* wrow = (const float4*)(Wc + (long)jj * 2 * DD);
    float4 acc = {0.f, 0.f, 0.f, 0.f};
    for (int iq = 0; iq < 256; ++iq) {
      float4 w = wrow[iq]; float4 d = din4[iq];
      acc.x += w.x*d.x; acc.y += w.y*d.y; acc.z += w.z*d.z; acc.w += w.w*d.w;
    }
    dvec[jj] = bc[jj] + acc.x + acc.y + acc.z + acc.w;
  }
  __syncthreads();

  if (tid < NCLS) {
    const float4* wrow = (const float4*)(Wd + (long)tid * DD);
    const float4* dv4 = (const float4*)dvec;
    float4 acc = {0.f, 0.f, 0.f, 0.f};
    for (int iq = 0; iq < 128; ++iq) {
      float4 w = wrow[iq]; float4 d = dv4[iq];
      acc.x += w.x*d.x; acc.y += w.y*d.y; acc.z += w.z*d.z; acc.w += w.w*d.w;
    }
    out[b * NCLS + tid] = bd[tid] + acc.x + acc.y + acc.z + acc.w;
  }
}

extern "C" void kernel_launch(void* const* d_in, const int* in_sizes, int n_in,
                              void* d_out, int out_size, void* d_ws, size_t ws_size,
                              hipStream_t stream)
{
  const int*   x    = (const int*)  d_in[0];
  const int*   eos  = (const int*)  d_in[1];
  const float* emb  = (const float*)d_in[2];
  const float* W_ih = (const float*)d_in[3];
  const float* W_hh = (const float*)d_in[4];
  const float* b_ih = (const float*)d_in[5];
  const float* b_hh = (const float*)d_in[6];
  const float* Wc   = (const float*)d_in[7];
  const float* bc   = (const float*)d_in[8];
  const float* Wd   = (const float*)d_in[9];
  const float* bd   = (const float*)d_in[10];
  float* out = (float*)d_out;

  // workspace: Abuf (h2+2) | Bbuf (xproj->h1+2) | flagA | flagB.
  // Poison 0xAA: value -3e-13 fails (>1 test); flag dword 0xAAAAAAAA != 1.
  const size_t vals   = (size_t)2 * NB * LL * DD * sizeof(float);  // 64 MB
  const size_t flagsz = (size_t)2 * NB * LL * 16 * sizeof(int);    //  2 MB
  float* Abuf = (float*)d_ws;
  float* Bbuf = Abuf + (size_t)NB * LL * DD;
  int* flagA = (int*)((char*)d_ws + vals);
  int* flagB = flagA + (size_t)NB * LL * 16;

  k_gemm_embed<<<1024, 256, 0, stream>>>(x, emb, W_ih, b_ih, b_hh, Bbuf);
  if (ws_size >= vals + flagsz) {
    k_scan_t<true><<<512, 256, 0, stream>>>(W_ih, W_hh, b_ih, b_hh,
                                            Bbuf, Abuf, flagB, flagA);
  } else {
    k_scan_t<false><<<512, 256, 0, stream>>>(W_ih, W_hh, b_ih, b_hh,
                                             Bbuf, Abuf, flagB, flagA);
  }
  k_attn<<<NB, 256, 0, stream>>>(Abuf, eos, Wc, bc, Wd, bd, out);
}

// Round 11
// 2000.693 us; speedup vs baseline: 1.7010x; 1.7010x over previous
//
#include <hip/hip_runtime.h>
#include <cmath>

#define NB   16
#define LL   1024
#define DD   512
#define NCLS 64

// ---------------------------------------------- fused embed-gather + proj GEMM
// 128x128 tile, 8x8 acc/thread, register prefetch 1 k-step ahead.
// C[m][n] = b1[n]+b2[n] + sum_k emb[x[m]][k] * W[n][k]   (M=16384, N=K=512)
// Roofline: 8.59 GFLOP @ 157 TF fp32 -> 55us floor; old 64x64 tile ran ~350us.
__global__ __launch_bounds__(256) void k_gemm_embed(
    const int* __restrict__ x, const float* __restrict__ emb,
    const float* __restrict__ W, const float* __restrict__ b1,
    const float* __restrict__ b2, float* __restrict__ C)
{
  __shared__ __align__(16) float As[16][132];  // [k][m], +4 pad
  __shared__ __align__(16) float Ws[16][132];  // [k][n], +4 pad
  const int tid = threadIdx.x;
  const int n0 = (blockIdx.x & 3) * 128;       // 4 n-tiles
  const int m0 = (blockIdx.x >> 2) * 128;      // 128 m-tiles -> 512 blocks
  const int tm = tid & 15, tn = tid >> 4;      // 16 x 16 thread grid
  float acc[8][8] = {};

  // staging: thread loads 2 float4 of row r at k-quads q*4 / q*4+4
  const int r = tid >> 1;           // 0..127
  const int q = (tid & 1) * 2;      // 0 or 2
  const long arow = (long)x[m0 + r] * DD;
  const long wrow = (long)(n0 + r) * DD;

  float4 a0 = *(const float4*)(emb + arow + q * 4);
  float4 a1 = *(const float4*)(emb + arow + q * 4 + 4);
  float4 w0 = *(const float4*)(W + wrow + q * 4);
  float4 w1 = *(const float4*)(W + wrow + q * 4 + 4);

  for (int k0 = 0; k0 < DD; k0 += 16) {
    __syncthreads();                 // previous compute done; LDS reusable
    As[q*4+0][r]=a0.x; As[q*4+1][r]=a0.y; As[q*4+2][r]=a0.z; As[q*4+3][r]=a0.w;
    As[q*4+4][r]=a1.x; As[q*4+5][r]=a1.y; As[q*4+6][r]=a1.z; As[q*4+7][r]=a1.w;
    Ws[q*4+0][r]=w0.x; Ws[q*4+1][r]=w0.y; Ws[q*4+2][r]=w0.z; Ws[q*4+3][r]=w0.w;
    Ws[q*4+4][r]=w1.x; Ws[q*4+5][r]=w1.y; Ws[q*4+6][r]=w1.z; Ws[q*4+7][r]=w1.w;
    if (k0 + 16 < DD) {              // prefetch next k-step; latency hidden
      a0 = *(const float4*)(emb + arow + k0 + 16 + q * 4);
      a1 = *(const float4*)(emb + arow + k0 + 16 + q * 4 + 4);
      w0 = *(const float4*)(W + wrow + k0 + 16 + q * 4);
      w1 = *(const float4*)(W + wrow + k0 + 16 + q * 4 + 4);
    }
    __syncthreads();
    #pragma unroll
    for (int kk = 0; kk < 16; ++kk) {
      // split rows/cols as base/base+64: 2-way bank alias (free) + broadcast
      float4 aL = *(const float4*)&As[kk][tm * 4];
      float4 aH = *(const float4*)&As[kk][64 + tm * 4];
      float4 wL = *(const float4*)&Ws[kk][tn * 4];
      float4 wH = *(const float4*)&Ws[kk][64 + tn * 4];
      const float av[8] = {aL.x,aL.y,aL.z,aL.w, aH.x,aH.y,aH.z,aH.w};
      const float wv[8] = {wL.x,wL.y,wL.z,wL.w, wH.x,wH.y,wH.z,wH.w};
      #pragma unroll
      for (int i = 0; i < 8; ++i)
        #pragma unroll
        for (int j = 0; j < 8; ++j)
          acc[i][j] += av[i] * wv[j];
    }
  }
  float bj[8];
  #pragma unroll
  for (int j = 0; j < 8; ++j) {
    const int c = n0 + ((j < 4) ? tn * 4 + j : 64 + tn * 4 + (j - 4));
    bj[j] = b1[c] + b2[c];
  }
  #pragma unroll
  for (int i = 0; i < 8; ++i) {
    const int m = m0 + ((i < 4) ? tm * 4 + i : 64 + tm * 4 + (i - 4));
    float4 o1 = { acc[i][0]+bj[0], acc[i][1]+bj[1], acc[i][2]+bj[2], acc[i][3]+bj[3] };
    float4 o2 = { acc[i][4]+bj[4], acc[i][5]+bj[5], acc[i][6]+bj[6], acc[i][7]+bj[7] };
    *(float4*)(C + (long)m * DD + n0 + tn * 4)      = o1;
    *(float4*)(C + (long)m * DD + n0 + 64 + tn * 4) = o2;
  }
}

// ---------------------------------------------------------------- scan helpers
template<int CTRL>
__device__ __forceinline__ float dpp_add(float x) {
  int s = __builtin_amdgcn_update_dpp(0, __float_as_int(x), CTRL, 0xF, 0xF, true);
  return x + __int_as_float(s);
}
__device__ __forceinline__ float wave_red8(float y) {
  y = dpp_add<0xB1>(y);    // quad_perm xor1
  y = dpp_add<0x4E>(y);    // quad_perm xor2
  y = dpp_add<0x141>(y);   // row_half_mirror (other quad of the 8-group)
  return y;
}

__device__ __forceinline__ float fast_tanh(float x) {
  float e = __expf(2.0f * x);
  return 1.0f - __fdividef(2.0f, 1.0f + e);
}

__device__ __forceinline__ float poll_ld(const float* p) {
  return __hip_atomic_load(p, __ATOMIC_RELAXED, __HIP_MEMORY_SCOPE_AGENT);
}
__device__ __forceinline__ void enc_st(float* p, float v) {
  __hip_atomic_store(p, v + 2.0f, __ATOMIC_RELAXED, __HIP_MEMORY_SCOPE_AGENT);
}
__device__ __forceinline__ void st_drain() {
  asm volatile("s_waitcnt vmcnt(0)" ::: "memory");
}
__device__ __forceinline__ void dot64(const float* w, const float4* h4, float4& a) {
  #pragma unroll
  for (int q = 0; q < 16; ++q) {
    float4 h = h4[q];
    a.x += w[4*q+0]*h.x; a.y += w[4*q+1]*h.y;
    a.z += w[4*q+2]*h.z; a.w += w[4*q+3]*h.w;
  }
}
__device__ __forceinline__ float hsum4(const float4& a) { return (a.x+a.y)+(a.z+a.w); }

// ------------------------------------------------- persistent 2-layer RNN scan
// EXACT R6 BANKED KERNEL (k_scan 1580us, total 2027us): value-poll handshake
// with s_sleep(2) backoff + vmcnt(0) drain after each handshake store.
// Verdict from r7/r9: flag protocols ADD a serialized L2 hop per step and lose;
// the value-poll is simultaneously the wait and the fetch. Do not touch.
__global__ __launch_bounds__(256, 2) void k_scan(
    const float* __restrict__ W_ih, const float* __restrict__ W_hh,
    const float* __restrict__ b_ih, const float* __restrict__ b_hh,
    float* __restrict__ Bbuf,   // in: xproj layer1 -> h1+2 (in-place, encoded)
    float* __restrict__ Abuf)   // h2+2 (O2, encoded)
{
  const int g = blockIdx.x;
  const int lay = g >> 8;          // 0: h1 chain, 1: h2 chain
  const int b = g & 15;            // batch
  const int j = (g & 255) >> 4;    // WG index within (layer,batch) [0,16)
  const int tid = threadIdx.x;
  const int part = tid & 7;        // k-part [0,8), 64 elems each
  const int rl  = tid >> 3;        // row_local [0,32)
  const int row = j * 32 + rl;     // global hidden row
  const bool leader = (part == 0);

  __shared__ __align__(16) float hS[2][8 * 68];  // recurrence-state stage, dbuf
  __shared__ __align__(16) float hT[2][8 * 68];  // h1 stage for layer-2's M2

  float* Bb = Bbuf + (long)b * LL * DD;
  float* Ab = Abuf + (long)b * LL * DD;

  const int i0 = tid, i1 = tid + 256;
  const int d0 = (i0 >> 6) * 68 + (i0 & 63);
  const int d1 = (i1 >> 6) * 68 + (i1 & 63);

  if (lay == 0) {
    // ------------ layer 1: h1(t) = tanh(xproj(t) + Whh1 . h1(t-1)) ----------
    float w1[64];
    {
      const float* p1 = W_hh + (long)row * DD + part * 64;
      #pragma unroll
      for (int q = 0; q < 64; ++q) w1[q] = p1[q];
    }
    #pragma unroll
    for (int q = 0; q < 64; ++q) asm volatile("" : "+v"(w1[q]));  // pin in VGPRs

    float xpv = 0.f, xnext = 0.f;
    if (leader) {
      xpv   = Bb[row];            // xproj(0)  (gemm completed: plain loads ok)
      xnext = Bb[DD + row];       // prefetch xproj(1) a full step ahead
      enc_st(Bb + row, fast_tanh(xpv));   // h1(0)
    }
    st_drain();
    for (int t = 1; t < LL; ++t) {
      const int bufi = t & 1;
      xpv = xnext;
      if (leader && (t + 1 < LL)) xnext = Bb[(long)(t + 1) * DD + row];
      // poll h1(t-1) — sleep-free first check, then backoff spin
      const float* s1 = Bb + (long)(t - 1) * DD;
      float v0 = poll_ld(s1 + i0), v1 = poll_ld(s1 + i1);
      while (fminf(v0, v1) <= 1.0f) {
        __builtin_amdgcn_s_sleep(2);
        v0 = poll_ld(s1 + i0); v1 = poll_ld(s1 + i1);
      }
      hS[bufi][d0] = v0 - 2.0f; hS[bufi][d1] = v1 - 2.0f;
      __syncthreads();
      float4 a = {0.f, 0.f, 0.f, 0.f};
      dot64(w1, (const float4*)&hS[bufi][part * 68], a);
      float y = wave_red8(hsum4(a));
      if (leader) enc_st(Bb + (long)t * DD + row, fast_tanh(xpv + y));
      st_drain();
    }
  } else {
    // ------ layer 2: h2(t) = tanh(Wih2.h1(t) + bias2 + Whh2.h2(t-1)) --------
    float w2[64], w3[64];
    {
      const float* p2 = W_ih + (long)DD * DD + (long)row * DD + part * 64;
      const float* p3 = W_hh + (long)DD * DD + (long)row * DD + part * 64;
      #pragma unroll
      for (int q = 0; q < 64; ++q) { w2[q] = p2[q]; w3[q] = p3[q]; }
    }
    #pragma unroll
    for (int q = 0; q < 64; ++q) {
      asm volatile("" : "+v"(w2[q]));
      asm volatile("" : "+v"(w3[q]));
    }
    const float bias2 = b_ih[DD + row] + b_hh[DD + row];

    // prologue: xin2(0) = Wih2 . h1(0) + bias2
    float xin2;
    {
      const float* s1 = Bb;   // h1(0), encoded (xproj < 1 until overwritten)
      float v0 = poll_ld(s1 + i0), v1 = poll_ld(s1 + i1);
      while (fminf(v0, v1) <= 1.0f) {
        __builtin_amdgcn_s_sleep(2);
        v0 = poll_ld(s1 + i0); v1 = poll_ld(s1 + i1);
      }
      hT[1][d0] = v0 - 2.0f; hT[1][d1] = v1 - 2.0f;
      __syncthreads();
      float4 a = {0.f, 0.f, 0.f, 0.f};
      dot64(w2, (const float4*)&hT[1][part * 68], a);
      xin2 = wave_red8(hsum4(a)) + bias2;
    }
    // iter t: store h2(t) (using xin2(t)), then compute xin2(t+1) from h1(t+1)
    // — M2 sits between the h2 store and the next poll, hiding store->poll.
    for (int t = 0; t < LL; ++t) {
      const int bufi = t & 1;
      const bool st2 = (t >= 1);        // h2(t-1) exists
      const bool st1 = (t + 1 < LL);    // need h1(t+1)
      {
        const float* s2 = Ab + (long)(t - 1) * DD;
        const float* s1 = Bb + (long)(t + 1) * DD;
        float u0 = 3.f, u1 = 3.f, v0 = 3.f, v1 = 3.f;
        if (st2) { u0 = poll_ld(s2 + i0); u1 = poll_ld(s2 + i1); }
        if (st1) { v0 = poll_ld(s1 + i0); v1 = poll_ld(s1 + i1); }
        while (fminf(fminf(u0, u1), fminf(v0, v1)) <= 1.0f) {
          __builtin_amdgcn_s_sleep(2);
          if (st2) { u0 = poll_ld(s2 + i0); u1 = poll_ld(s2 + i1); }
          if (st1) { v0 = poll_ld(s1 + i0); v1 = poll_ld(s1 + i1); }
        }
        if (st2) { hS[bufi][d0] = u0 - 2.0f; hS[bufi][d1] = u1 - 2.0f; }
        if (st1) { hT[bufi][d0] = v0 - 2.0f; hT[bufi][d1] = v1 - 2.0f; }
      }
      __syncthreads();
      // M3: h2(t) = tanh(xin2(t) + Whh2 . h2(t-1))
      float y3 = 0.f;
      if (st2) {
        float4 a = {0.f, 0.f, 0.f, 0.f};
        dot64(w3, (const float4*)&hS[bufi][part * 68], a);
        y3 = hsum4(a);
      }
      y3 = wave_red8(y3);
      if (leader) enc_st(Ab + (long)t * DD + row, fast_tanh(xin2 + y3));
      st_drain();
      // M2: xin2(t+1) = Wih2 . h1(t+1) + bias2 (off the h2 critical hop)
      if (st1) {
        float4 a = {0.f, 0.f, 0.f, 0.f};
        dot64(w2, (const float4*)&hT[bufi][part * 68], a);
        xin2 = wave_red8(hsum4(a)) + bias2;
      }
    }
  }
}

// ------------------------------------------- attention row @ eos + decode head
// O2 is stored ENCODED (h+2). Decode: q explicitly; scores via qsum trick;
// att_z via sum(p)=1 -> subtract 2 at the end.
__global__ __launch_bounds__(256) void k_attn(
    const float* __restrict__ O2, const int* __restrict__ eos,
    const float* __restrict__ Wc, const float* __restrict__ bc,
    const float* __restrict__ Wd, const float* __restrict__ bd,
    float* __restrict__ out)
{
  const int b = blockIdx.x;
  const int tid = threadIdx.x;
  const int te = eos[b];
  __shared__ __align__(16) float q[DD];
  __shared__ float ps[LL];
  __shared__ float red[256];
  __shared__ __align__(16) float din[2 * DD];
  __shared__ __align__(16) float dvec[DD];
  const float* Ob = O2 + (long)b * LL * DD;
  const float4* Ob4 = (const float4*)Ob;

  float qpart = 0.f;
  for (int i = tid; i < DD; i += 256) {
    float v = Ob[(long)te * DD + i] - 2.0f;   // decode
    q[i] = v; qpart += v;
  }
  red[tid] = qpart; __syncthreads();
  for (int off = 128; off > 0; off >>= 1) {
    if (tid < off) red[tid] += red[tid + off];
    __syncthreads();
  }
  const float qsum = red[0];
  __syncthreads();
  const float4* q4 = (const float4*)q;

  // masked scores: raw dot(o_enc, q) - 2*qsum == dot(o, q)
  for (int ss = tid; ss < LL; ss += 256) {
    float sc = -1.0e9f;
    if (ss < te) {
      float4 acc = {0.f, 0.f, 0.f, 0.f};
      for (int kq = 0; kq < 128; ++kq) {
        float4 o = Ob4[ss * 128 + kq];
        float4 qq = q4[kq];
        acc.x += o.x*qq.x; acc.y += o.y*qq.y; acc.z += o.z*qq.z; acc.w += o.w*qq.w;
      }
      sc = acc.x + acc.y + acc.z + acc.w - 2.0f * qsum;
    }
    ps[ss] = sc;
  }
  __syncthreads();
  float m = -3.0e38f;
  for (int ss = tid; ss < LL; ss += 256) m = fmaxf(m, ps[ss]);
  red[tid] = m; __syncthreads();
  for (int off = 128; off > 0; off >>= 1) {
    if (tid < off) red[tid] = fmaxf(red[tid], red[tid + off]);
    __syncthreads();
  }
  m = red[0]; __syncthreads();
  float lsum = 0.f;
  for (int ss = tid; ss < LL; ss += 256) {
    float e = expf(ps[ss] - m);
    ps[ss] = e; lsum += e;
  }
  __syncthreads();
  red[tid] = lsum; __syncthreads();
  for (int off = 128; off > 0; off >>= 1) {
    if (tid < off) red[tid] += red[tid + off];
    __syncthreads();
  }
  const float inv = 1.0f / red[0];
  __syncthreads();
  for (int ss = tid; ss < LL; ss += 256) ps[ss] *= inv;
  __syncthreads();

  // att_z (encoded: sum p*o_enc - 2 since sum p = 1), z-copy (already decoded)
  if (tid < 128) {
    float4 acc = {0.f, 0.f, 0.f, 0.f};
    for (int ss = 0; ss < LL; ++ss) {
      float p = ps[ss];
      if (p != 0.0f) {
        float4 o = Ob4[ss * 128 + tid];
        acc.x += p*o.x; acc.y += p*o.y; acc.z += p*o.z; acc.w += p*o.w;
      }
    }
    acc.x -= 2.0f; acc.y -= 2.0f; acc.z -= 2.0f; acc.w -= 2.0f;
    ((float4*)din)[tid] = acc;
  } else {
    const int c = tid - 128;
    ((float4*)din)[128 + c] = q4[c];
  }
  __syncthreads();

  const float4* din4 = (const float4*)din;
  for (int jj = tid; jj < DD; jj += 256) {
    const float4* wrow = (const float4*)(Wc + (long)jj * 2 * DD);
    float4 acc = {0.f, 0.f, 0.f, 0.f};
    for (int iq = 0; iq < 256; ++iq) {
      float4 w = wrow[iq]; float4 d = din4[iq];
      acc.x += w.x*d.x; acc.y += w.y*d.y; acc.z += w.z*d.z; acc.w += w.w*d.w;
    }
    dvec[jj] = bc[jj] + acc.x + acc.y + acc.z + acc.w;
  }
  __syncthreads();

  if (tid < NCLS) {
    const float4* wrow = (const float4*)(Wd + (long)tid * DD);
    const float4* dv4 = (const float4*)dvec;
    float4 acc = {0.f, 0.f, 0.f, 0.f};
    for (int iq = 0; iq < 128; ++iq) {
      float4 w = wrow[iq]; float4 d = dv4[iq];
      acc.x += w.x*d.x; acc.y += w.y*d.y; acc.z += w.z*d.z; acc.w += w.w*d.w;
    }
    out[b * NCLS + tid] = bd[tid] + acc.x + acc.y + acc.z + acc.w;
  }
}

extern "C" void kernel_launch(void* const* d_in, const int* in_sizes, int n_in,
                              void* d_out, int out_size, void* d_ws, size_t ws_size,
                              hipStream_t stream)
{
  const int*   x    = (const int*)  d_in[0];
  const int*   eos  = (const int*)  d_in[1];
  const float* emb  = (const float*)d_in[2];
  const float* W_ih = (const float*)d_in[3];
  const float* W_hh = (const float*)d_in[4];
  const float* b_ih = (const float*)d_in[5];
  const float* b_hh = (const float*)d_in[6];
  const float* Wc   = (const float*)d_in[7];
  const float* bc   = (const float*)d_in[8];
  const float* Wd   = (const float*)d_in[9];
  const float* bd   = (const float*)d_in[10];
  float* out = (float*)d_out;

  // workspace: Abuf (h2+2) | Bbuf (xproj->h1+2). Poison 0xAA = -3e-13 < 1 => "not ready".
  float* Abuf = (float*)d_ws;
  float* Bbuf = Abuf + (size_t)NB * LL * DD;

  k_gemm_embed<<<512, 256, 0, stream>>>(x, emb, W_ih, b_ih, b_hh, Bbuf);
  k_scan<<<512, 256, 0, stream>>>(W_ih, W_hh, b_ih, b_hh, Bbuf, Abuf);
  k_attn<<<NB, 256, 0, stream>>>(Abuf, eos, Wc, bc, Wd, bd, out);
}

// Round 12
// 1748.449 us; speedup vs baseline: 1.9465x; 1.1443x over previous
//
#include <hip/hip_runtime.h>
#include <cmath>

#define NB   16
#define LL   1024
#define DD   512
#define NCLS 64

// ---------------------------------------------- fused embed-gather + proj GEMM
// 128x128 tile, 8x8 acc/thread, register prefetch 1 k-step ahead. (r11, banked)
__global__ __launch_bounds__(256) void k_gemm_embed(
    const int* __restrict__ x, const float* __restrict__ emb,
    const float* __restrict__ W, const float* __restrict__ b1,
    const float* __restrict__ b2, float* __restrict__ C)
{
  __shared__ __align__(16) float As[16][132];  // [k][m], +4 pad
  __shared__ __align__(16) float Ws[16][132];  // [k][n], +4 pad
  const int tid = threadIdx.x;
  const int n0 = (blockIdx.x & 3) * 128;       // 4 n-tiles
  const int m0 = (blockIdx.x >> 2) * 128;      // 128 m-tiles -> 512 blocks
  const int tm = tid & 15, tn = tid >> 4;      // 16 x 16 thread grid
  float acc[8][8] = {};

  const int r = tid >> 1;           // 0..127
  const int q = (tid & 1) * 2;      // 0 or 2
  const long arow = (long)x[m0 + r] * DD;
  const long wrow = (long)(n0 + r) * DD;

  float4 a0 = *(const float4*)(emb + arow + q * 4);
  float4 a1 = *(const float4*)(emb + arow + q * 4 + 4);
  float4 w0 = *(const float4*)(W + wrow + q * 4);
  float4 w1 = *(const float4*)(W + wrow + q * 4 + 4);

  for (int k0 = 0; k0 < DD; k0 += 16) {
    __syncthreads();
    As[q*4+0][r]=a0.x; As[q*4+1][r]=a0.y; As[q*4+2][r]=a0.z; As[q*4+3][r]=a0.w;
    As[q*4+4][r]=a1.x; As[q*4+5][r]=a1.y; As[q*4+6][r]=a1.z; As[q*4+7][r]=a1.w;
    Ws[q*4+0][r]=w0.x; Ws[q*4+1][r]=w0.y; Ws[q*4+2][r]=w0.z; Ws[q*4+3][r]=w0.w;
    Ws[q*4+4][r]=w1.x; Ws[q*4+5][r]=w1.y; Ws[q*4+6][r]=w1.z; Ws[q*4+7][r]=w1.w;
    if (k0 + 16 < DD) {
      a0 = *(const float4*)(emb + arow + k0 + 16 + q * 4);
      a1 = *(const float4*)(emb + arow + k0 + 16 + q * 4 + 4);
      w0 = *(const float4*)(W + wrow + k0 + 16 + q * 4);
      w1 = *(const float4*)(W + wrow + k0 + 16 + q * 4 + 4);
    }
    __syncthreads();
    #pragma unroll
    for (int kk = 0; kk < 16; ++kk) {
      float4 aL = *(const float4*)&As[kk][tm * 4];
      float4 aH = *(const float4*)&As[kk][64 + tm * 4];
      float4 wL = *(const float4*)&Ws[kk][tn * 4];
      float4 wH = *(const float4*)&Ws[kk][64 + tn * 4];
      const float av[8] = {aL.x,aL.y,aL.z,aL.w, aH.x,aH.y,aH.z,aH.w};
      const float wv[8] = {wL.x,wL.y,wL.z,wL.w, wH.x,wH.y,wH.z,wH.w};
      #pragma unroll
      for (int i = 0; i < 8; ++i)
        #pragma unroll
        for (int j = 0; j < 8; ++j)
          acc[i][j] += av[i] * wv[j];
    }
  }
  float bj[8];
  #pragma unroll
  for (int j = 0; j < 8; ++j) {
    const int c = n0 + ((j < 4) ? tn * 4 + j : 64 + tn * 4 + (j - 4));
    bj[j] = b1[c] + b2[c];
  }
  #pragma unroll
  for (int i = 0; i < 8; ++i) {
    const int m = m0 + ((i < 4) ? tm * 4 + i : 64 + tm * 4 + (i - 4));
    float4 o1 = { acc[i][0]+bj[0], acc[i][1]+bj[1], acc[i][2]+bj[2], acc[i][3]+bj[3] };
    float4 o2 = { acc[i][4]+bj[4], acc[i][5]+bj[5], acc[i][6]+bj[6], acc[i][7]+bj[7] };
    *(float4*)(C + (long)m * DD + n0 + tn * 4)      = o1;
    *(float4*)(C + (long)m * DD + n0 + 64 + tn * 4) = o2;
  }
}

// ---------------------------------------------------------------- scan helpers
template<int CTRL>
__device__ __forceinline__ float dpp_add(float x) {
  int s = __builtin_amdgcn_update_dpp(0, __float_as_int(x), CTRL, 0xF, 0xF, true);
  return x + __int_as_float(s);
}
__device__ __forceinline__ float wave_red8(float y) {
  y = dpp_add<0xB1>(y);    // quad_perm xor1
  y = dpp_add<0x4E>(y);    // quad_perm xor2
  y = dpp_add<0x141>(y);   // row_half_mirror (other quad of the 8-group)
  return y;
}

__device__ __forceinline__ float fast_tanh(float x) {
  float e = __expf(2.0f * x);
  return 1.0f - __fdividef(2.0f, 1.0f + e);
}

__device__ __forceinline__ float poll_ld(const float* p) {
  return __hip_atomic_load(p, __ATOMIC_RELAXED, __HIP_MEMORY_SCOPE_AGENT);
}
__device__ __forceinline__ void enc_st(float* p, float v) {
  __hip_atomic_store(p, v + 2.0f, __ATOMIC_RELAXED, __HIP_MEMORY_SCOPE_AGENT);
}
__device__ __forceinline__ void st_drain() {
  asm volatile("s_waitcnt vmcnt(0)" ::: "memory");
}
__device__ __forceinline__ void dot64(const float* w, const float4* h4, float4& a) {
  #pragma unroll
  for (int q = 0; q < 16; ++q) {
    float4 h = h4[q];
    a.x += w[4*q+0]*h.x; a.y += w[4*q+1]*h.y;
    a.z += w[4*q+2]*h.z; a.w += w[4*q+3]*h.w;
  }
}
__device__ __forceinline__ float hsum4(const float4& a) { return (a.x+a.y)+(a.z+a.w); }

// ------------------------------- persistent 2-layer RNN scan + fused attn tail
// R6/R11 BANKED chain protocol (value-poll + s_sleep(2) + drain). Two changes:
//  (1) layer-2 per-step order is now store -> M2 -> drain -> poll: the drain's
//      ~300cy L2 round-trip overlaps M2's FMA work instead of serializing
//      (throttle semantics preserved: still drains before the poll flood).
//  (2) ATTN IS FUSED: layer-1 WG j==0 of each batch, after its h1 chain ends,
//      polls h2(LL-1) of its batch (full row >1 <=> all layer-2 WGs done, since
//      each writes t in order) and runs the attention+decode tail in-place.
//      Attn for batch b starts when BATCH B finishes — no launch gap, no
//      all-batch skew. DAG: attn <- layer-2 <- layer-1; all 512 WGs resident.
__global__ __launch_bounds__(256, 2) void k_scan(
    const float* __restrict__ W_ih, const float* __restrict__ W_hh,
    const float* __restrict__ b_ih, const float* __restrict__ b_hh,
    float* __restrict__ Bbuf,   // in: xproj layer1 -> h1+2 (in-place, encoded)
    float* __restrict__ Abuf,   // h2+2 (O2, encoded)
    const int* __restrict__ eos,
    const float* __restrict__ Wc, const float* __restrict__ bc,
    const float* __restrict__ Wd, const float* __restrict__ bd,
    float* __restrict__ out)
{
  const int g = blockIdx.x;
  const int lay = g >> 8;          // 0: h1 chain, 1: h2 chain
  const int b = g & 15;            // batch
  const int j = (g & 255) >> 4;    // WG index within (layer,batch) [0,16)
  const int tid = threadIdx.x;
  const int part = tid & 7;        // k-part [0,8), 64 elems each
  const int rl  = tid >> 3;        // row_local [0,32)
  const int row = j * 32 + rl;     // global hidden row
  const bool leader = (part == 0);

  // union: chain stage (2176 floats) / attn buffers (3328 floats)
  __shared__ __align__(16) float smem[3328];
  float* hS = smem;                // [2][544] recurrence-state stage, dbuf
  float* hT = smem + 1088;         // [2][544] h1 stage for layer-2's M2

  float* Bb = Bbuf + (long)b * LL * DD;
  float* Ab = Abuf + (long)b * LL * DD;

  const int i0 = tid, i1 = tid + 256;
  const int d0 = (i0 >> 6) * 68 + (i0 & 63);
  const int d1 = (i1 >> 6) * 68 + (i1 & 63);

  if (lay == 0) {
    // ------------ layer 1: h1(t) = tanh(xproj(t) + Whh1 . h1(t-1)) ----------
    {
      float w1[64];
      {
        const float* p1 = W_hh + (long)row * DD + part * 64;
        #pragma unroll
        for (int q = 0; q < 64; ++q) w1[q] = p1[q];
      }
      #pragma unroll
      for (int q = 0; q < 64; ++q) asm volatile("" : "+v"(w1[q]));  // pin

      float xpv = 0.f, xnext = 0.f;
      if (leader) {
        xpv   = Bb[row];            // xproj(0)  (gemm completed)
        xnext = Bb[DD + row];       // prefetch xproj(1) a full step ahead
        enc_st(Bb + row, fast_tanh(xpv));   // h1(0)
      }
      st_drain();
      for (int t = 1; t < LL; ++t) {
        const int bufi = t & 1;
        xpv = xnext;
        if (leader && (t + 1 < LL)) xnext = Bb[(long)(t + 1) * DD + row];
        // poll h1(t-1) — sleep-free first check, then backoff spin
        const float* s1 = Bb + (long)(t - 1) * DD;
        float v0 = poll_ld(s1 + i0), v1 = poll_ld(s1 + i1);
        while (fminf(v0, v1) <= 1.0f) {
          __builtin_amdgcn_s_sleep(2);
          v0 = poll_ld(s1 + i0); v1 = poll_ld(s1 + i1);
        }
        hS[bufi*544 + d0] = v0 - 2.0f; hS[bufi*544 + d1] = v1 - 2.0f;
        __syncthreads();
        float4 a = {0.f, 0.f, 0.f, 0.f};
        dot64(w1, (const float4*)&hS[bufi*544 + part * 68], a);
        float y = wave_red8(hsum4(a));
        if (leader) enc_st(Bb + (long)t * DD + row, fast_tanh(xpv + y));
        st_drain();
      }
    }
    if (j != 0) return;

    // ---------------- fused attention + decode tail (one WG per batch) ------
    // wait for this batch's h2 to complete: final row all-ready
    {
      const float* fin = Ab + (long)(LL - 1) * DD;
      float v0 = poll_ld(fin + i0), v1 = poll_ld(fin + i1);
      while (fminf(v0, v1) <= 1.0f) {
        __builtin_amdgcn_s_sleep(2);
        v0 = poll_ld(fin + i0); v1 = poll_ld(fin + i1);
      }
    }
    __syncthreads();                 // chain-LDS dead; safe to re-alias
    float* q    = smem;              // 512
    float* ps   = smem + 512;        // 1024
    float* red  = smem + 1536;       // 256
    float* din  = smem + 1792;       // 1024
    float* dvec = smem + 2816;       // 512
    const int te = eos[b];
    const float* Ob = Ab;            // encoded h2+2
    const float4* Ob4 = (const float4*)Ob;

    float qpart = 0.f;
    for (int i = tid; i < DD; i += 256) {
      float v = poll_ld(Ob + (long)te * DD + i) - 2.0f;   // decode
      q[i] = v; qpart += v;
    }
    red[tid] = qpart; __syncthreads();
    for (int off = 128; off > 0; off >>= 1) {
      if (tid < off) red[tid] += red[tid + off];
      __syncthreads();
    }
    const float qsum = red[0];
    __syncthreads();
    const float4* q4 = (const float4*)q;

    // masked scores: raw dot(o_enc, q) - 2*qsum == dot(o, q)
    for (int ss = tid; ss < LL; ss += 256) {
      float sc = -1.0e9f;
      if (ss < te) {
        float4 acc = {0.f, 0.f, 0.f, 0.f};
        for (int kq = 0; kq < 128; ++kq) {
          float4 o = Ob4[ss * 128 + kq];
          float4 qq = q4[kq];
          acc.x += o.x*qq.x; acc.y += o.y*qq.y; acc.z += o.z*qq.z; acc.w += o.w*qq.w;
        }
        sc = acc.x + acc.y + acc.z + acc.w - 2.0f * qsum;
      }
      ps[ss] = sc;
    }
    __syncthreads();
    float m = -3.0e38f;
    for (int ss = tid; ss < LL; ss += 256) m = fmaxf(m, ps[ss]);
    red[tid] = m; __syncthreads();
    for (int off = 128; off > 0; off >>= 1) {
      if (tid < off) red[tid] = fmaxf(red[tid], red[tid + off]);
      __syncthreads();
    }
    m = red[0]; __syncthreads();
    float lsum = 0.f;
    for (int ss = tid; ss < LL; ss += 256) {
      float e = expf(ps[ss] - m);
      ps[ss] = e; lsum += e;
    }
    __syncthreads();
    red[tid] = lsum; __syncthreads();
    for (int off = 128; off > 0; off >>= 1) {
      if (tid < off) red[tid] += red[tid + off];
      __syncthreads();
    }
    const float inv = 1.0f / red[0];
    __syncthreads();
    for (int ss = tid; ss < LL; ss += 256) ps[ss] *= inv;
    __syncthreads();

    // att_z (encoded: sum p*o_enc - 2 since sum p = 1), z-copy (decoded)
    if (tid < 128) {
      float4 acc = {0.f, 0.f, 0.f, 0.f};
      for (int ss = 0; ss < LL; ++ss) {
        float p = ps[ss];
        if (p != 0.0f) {
          float4 o = Ob4[ss * 128 + tid];
          acc.x += p*o.x; acc.y += p*o.y; acc.z += p*o.z; acc.w += p*o.w;
        }
      }
      acc.x -= 2.0f; acc.y -= 2.0f; acc.z -= 2.0f; acc.w -= 2.0f;
      ((float4*)din)[tid] = acc;
    } else {
      const int c = tid - 128;
      ((float4*)din)[128 + c] = q4[c];
    }
    __syncthreads();

    const float4* din4 = (const float4*)din;
    for (int jj = tid; jj < DD; jj += 256) {
      const float4* wrow = (const float4*)(Wc + (long)jj * 2 * DD);
      float4 acc = {0.f, 0.f, 0.f, 0.f};
      for (int iq = 0; iq < 256; ++iq) {
        float4 w = wrow[iq]; float4 d = din4[iq];
        acc.x += w.x*d.x; acc.y += w.y*d.y; acc.z += w.z*d.z; acc.w += w.w*d.w;
      }
      dvec[jj] = bc[jj] + acc.x + acc.y + acc.z + acc.w;
    }
    __syncthreads();

    if (tid < NCLS) {
      const float4* wrow = (const float4*)(Wd + (long)tid * DD);
      const float4* dv4 = (const float4*)dvec;
      float4 acc = {0.f, 0.f, 0.f, 0.f};
      for (int iq = 0; iq < 128; ++iq) {
        float4 w = wrow[iq]; float4 d = dv4[iq];
        acc.x += w.x*d.x; acc.y += w.y*d.y; acc.z += w.z*d.z; acc.w += w.w*d.w;
      }
      out[b * NCLS + tid] = bd[tid] + acc.x + acc.y + acc.z + acc.w;
    }
  } else {
    // ------ layer 2: h2(t) = tanh(Wih2.h1(t) + bias2 + Whh2.h2(t-1)) --------
    float w2[64], w3[64];
    {
      const float* p2 = W_ih + (long)DD * DD + (long)row * DD + part * 64;
      const float* p3 = W_hh + (long)DD * DD + (long)row * DD + part * 64;
      #pragma unroll
      for (int q = 0; q < 64; ++q) { w2[q] = p2[q]; w3[q] = p3[q]; }
    }
    #pragma unroll
    for (int q = 0; q < 64; ++q) {
      asm volatile("" : "+v"(w2[q]));
      asm volatile("" : "+v"(w3[q]));
    }
    const float bias2 = b_ih[DD + row] + b_hh[DD + row];

    // prologue: xin2(0) = Wih2 . h1(0) + bias2
    float xin2;
    {
      const float* s1 = Bb;   // h1(0), encoded
      float v0 = poll_ld(s1 + i0), v1 = poll_ld(s1 + i1);
      while (fminf(v0, v1) <= 1.0f) {
        __builtin_amdgcn_s_sleep(2);
        v0 = poll_ld(s1 + i0); v1 = poll_ld(s1 + i1);
      }
      hT[544 + d0] = v0 - 2.0f; hT[544 + d1] = v1 - 2.0f;
      __syncthreads();
      float4 a = {0.f, 0.f, 0.f, 0.f};
      dot64(w2, (const float4*)&hT[544 + part * 68], a);
      xin2 = wave_red8(hsum4(a)) + bias2;
    }
    // iter t: poll -> stage -> M3 -> store h2(t) -> M2 -> drain -> next
    for (int t = 0; t < LL; ++t) {
      const int bufi = t & 1;
      const bool st2 = (t >= 1);        // h2(t-1) exists
      const bool st1 = (t + 1 < LL);    // need h1(t+1)
      {
        const float* s2 = Ab + (long)(t - 1) * DD;
        const float* s1 = Bb + (long)(t + 1) * DD;
        float u0 = 3.f, u1 = 3.f, v0 = 3.f, v1 = 3.f;
        if (st2) { u0 = poll_ld(s2 + i0); u1 = poll_ld(s2 + i1); }
        if (st1) { v0 = poll_ld(s1 + i0); v1 = poll_ld(s1 + i1); }
        while (fminf(fminf(u0, u1), fminf(v0, v1)) <= 1.0f) {
          __builtin_amdgcn_s_sleep(2);
          if (st2) { u0 = poll_ld(s2 + i0); u1 = poll_ld(s2 + i1); }
          if (st1) { v0 = poll_ld(s1 + i0); v1 = poll_ld(s1 + i1); }
        }
        if (st2) { hS[bufi*544 + d0] = u0 - 2.0f; hS[bufi*544 + d1] = u1 - 2.0f; }
        if (st1) { hT[bufi*544 + d0] = v0 - 2.0f; hT[bufi*544 + d1] = v1 - 2.0f; }
      }
      __syncthreads();
      // M3: h2(t) = tanh(xin2(t) + Whh2 . h2(t-1))
      float y3 = 0.f;
      if (st2) {
        float4 a = {0.f, 0.f, 0.f, 0.f};
        dot64(w3, (const float4*)&hS[bufi*544 + part * 68], a);
        y3 = hsum4(a);
      }
      y3 = wave_red8(y3);
      if (leader) enc_st(Ab + (long)t * DD + row, fast_tanh(xin2 + y3));
      // M2 BEFORE drain: FMA work overlaps the store's L2 commit window.
      if (st1) {
        float4 a = {0.f, 0.f, 0.f, 0.f};
        dot64(w2, (const float4*)&hT[bufi*544 + part * 68], a);
        xin2 = wave_red8(hsum4(a)) + bias2;
      }
      st_drain();
    }
  }
}

extern "C" void kernel_launch(void* const* d_in, const int* in_sizes, int n_in,
                              void* d_out, int out_size, void* d_ws, size_t ws_size,
                              hipStream_t stream)
{
  const int*   x    = (const int*)  d_in[0];
  const int*   eos  = (const int*)  d_in[1];
  const float* emb  = (const float*)d_in[2];
  const float* W_ih = (const float*)d_in[3];
  const float* W_hh = (const float*)d_in[4];
  const float* b_ih = (const float*)d_in[5];
  const float* b_hh = (const float*)d_in[6];
  const float* Wc   = (const float*)d_in[7];
  const float* bc   = (const float*)d_in[8];
  const float* Wd   = (const float*)d_in[9];
  const float* bd   = (const float*)d_in[10];
  float* out = (float*)d_out;

  // workspace: Abuf (h2+2) | Bbuf (xproj->h1+2). Poison 0xAA = -3e-13 < 1 => "not ready".
  float* Abuf = (float*)d_ws;
  float* Bbuf = Abuf + (size_t)NB * LL * DD;

  k_gemm_embed<<<512, 256, 0, stream>>>(x, emb, W_ih, b_ih, b_hh, Bbuf);
  k_scan<<<512, 256, 0, stream>>>(W_ih, W_hh, b_ih, b_hh, Bbuf, Abuf,
                                  eos, Wc, bc, Wd, bd, out);
}